// Round 5
// baseline (852.036 us; speedup 1.0000x reference)
//
#include <hip/hip_runtime.h>
#include <hip/hip_bf16.h>

// Problem constants (match reference)
constexpr int B = 8192;
constexpr int G = 1024;
constexpr int E = 256;
constexpr int K = 2048;
constexpr float P_NULL = 0.1f;
constexpr int N_STEP = 4;

typedef unsigned short u16;
typedef short bf16x8 __attribute__((ext_vector_type(8)));
typedef float f32x4 __attribute__((ext_vector_type(4)));

// ---------------------------------------------------------------------------
// bf16 <-> f32 (RNE)
// ---------------------------------------------------------------------------
__device__ inline u16 f2bf(float f) {
    union { float f; uint32_t u; } cv;
    cv.f = f;
    const uint32_t u = cv.u;
    return (u16)((u + 0x7fffu + ((u >> 16) & 1u)) >> 16);
}
__device__ inline float bf2f(u16 h) {
    union { uint32_t u; float f; } cv;
    cv.u = ((uint32_t)h) << 16;
    return cv.f;
}
__device__ inline void unpack8(uint4 u, float* v) {
    v[0] = bf2f((u16)(u.x & 0xffff)); v[1] = bf2f((u16)(u.x >> 16));
    v[2] = bf2f((u16)(u.y & 0xffff)); v[3] = bf2f((u16)(u.y >> 16));
    v[4] = bf2f((u16)(u.z & 0xffff)); v[5] = bf2f((u16)(u.z >> 16));
    v[6] = bf2f((u16)(u.w & 0xffff)); v[7] = bf2f((u16)(u.w >> 16));
}
__device__ inline uint4 pack8(const float* v) {
    uint4 u;
    u.x = (uint32_t)f2bf(v[0]) | ((uint32_t)f2bf(v[1]) << 16);
    u.y = (uint32_t)f2bf(v[2]) | ((uint32_t)f2bf(v[3]) << 16);
    u.z = (uint32_t)f2bf(v[4]) | ((uint32_t)f2bf(v[5]) << 16);
    u.w = (uint32_t)f2bf(v[6]) | ((uint32_t)f2bf(v[7]) << 16);
    return u;
}

// async global->LDS, 16B per lane
typedef __attribute__((address_space(1))) const void* gaddr_t;
typedef __attribute__((address_space(3))) void* laddr_t;
__device__ inline void gload_lds16(const void* g, void* l) {
    __builtin_amdgcn_global_load_lds((gaddr_t)g, (laddr_t)l, 16, 0, 0);
}

// XCD-aware tile swizzle (requires gridDim.y % 8 == 0)
__device__ inline void swizzle_tiles(int& tr, int& tc) {
    const int cx = gridDim.x, cy = gridDim.y;
    const int id = blockIdx.y * cx + blockIdx.x;
    const int k = id & 7;
    const int q = id >> 3;
    tr = k * (cy >> 3) + q / cx;
    tc = q % cx;
}

// ---------------------------------------------------------------------------
// Reduction helpers (256-thread blocks, wave64)
// ---------------------------------------------------------------------------
__device__ inline float wave_sum(float v) {
#pragma unroll
    for (int off = 32; off > 0; off >>= 1) v += __shfl_down(v, off, 64);
    return v;
}
__device__ inline float wave_max(float v) {
#pragma unroll
    for (int off = 32; off > 0; off >>= 1) v = fmaxf(v, __shfl_down(v, off, 64));
    return v;
}
__device__ inline float block_sum256(float v, float* sm) {
    v = wave_sum(v);
    const int w = threadIdx.x >> 6;
    if ((threadIdx.x & 63) == 0) sm[w] = v;
    __syncthreads();
    const float r = sm[0] + sm[1] + sm[2] + sm[3];
    __syncthreads();
    return r;
}
__device__ inline float block_max256(float v, float* sm) {
    v = wave_max(v);
    const int w = threadIdx.x >> 6;
    if ((threadIdx.x & 63) == 0) sm[w] = v;
    __syncthreads();
    const float r = fmaxf(fmaxf(sm[0], sm[1]), fmaxf(sm[2], sm[3]));
    __syncthreads();
    return r;
}

// ---------------------------------------------------------------------------
// f32 -> bf16 flat convert, 8 elems/thread
// ---------------------------------------------------------------------------
__global__ __launch_bounds__(256) void f2bf_kernel(
    const float* __restrict__ in, u16* __restrict__ out, int n) {
    const int i = (blockIdx.x * 256 + threadIdx.x) * 8;
    if (i + 7 >= n) {
        for (int j = i; j < n; ++j) out[j] = f2bf(in[j]);
        return;
    }
    const float4 a = *(const float4*)(in + i);
    const float4 b = *(const float4*)(in + i + 4);
    float v[8] = {a.x, a.y, a.z, a.w, b.x, b.y, b.z, b.w};
    *(uint4*)(out + i) = pack8(v);
}

// ---------------------------------------------------------------------------
// f32 (R,C) -> bf16 (C,R) transpose. grid (C/32, R/32), block 256.
// ---------------------------------------------------------------------------
__global__ __launch_bounds__(256) void transpose_bf_kernel(
    const float* __restrict__ in, u16* __restrict__ out, int R, int C) {
    __shared__ float tile[32][33];
    const int bx = blockIdx.x * 32, by = blockIdx.y * 32;
    const int x = threadIdx.x & 31, y0 = threadIdx.x >> 5;
#pragma unroll
    for (int yy = 0; yy < 32; yy += 8)
        tile[y0 + yy][x] = in[(size_t)(by + y0 + yy) * C + bx + x];
    __syncthreads();
#pragma unroll
    for (int yy = 0; yy < 32; yy += 8)
        out[(size_t)(bx + y0 + yy) * R + by + x] = f2bf(tile[x][y0 + yy]);
}

// ---------------------------------------------------------------------------
// Column mean-of-squares (f32 in): out[k] += inv_rows * sum_r M[r,k]^2
// ---------------------------------------------------------------------------
__global__ __launch_bounds__(256) void colsq_kernel(
    const float* __restrict__ M, int rows, int cols, float inv_rows,
    float* __restrict__ out) {
    const int k = blockIdx.x * 256 + threadIdx.x;
    const int r0 = blockIdx.y * 128;
    const int r1 = min(r0 + 128, rows);
    float s = 0.f;
    for (int r = r0; r < r1; ++r) {
        const float v = M[(size_t)r * cols + k];
        s = fmaf(v, v, s);
    }
    atomicAdd(out + k, s * inv_rows);
}

// ---------------------------------------------------------------------------
// MFMA bf16 GEMM (128x128 tile): C = A(M,Kd) x Bm(N,Kd)^T
// ---------------------------------------------------------------------------
enum { EPI_BIAS_BF16 = 0, EPI_BF16 = 1, EPI_LOSS = 2 };
constexpr int STG = 136;

template <int EPI>
__global__ __launch_bounds__(256) void mfma_gemm_kernel(
    const u16* __restrict__ A, const u16* __restrict__ Bm,
    void* __restrict__ Cout, const float* __restrict__ bias,
    const float* __restrict__ X, int M, int N, int Kd, float alpha) {
    __shared__ u16 smem[17408];
    u16* As = smem;
    u16* Bs = smem + 8192;
    const int tid = threadIdx.x;
    int btr, btc;
    swizzle_tiles(btr, btc);
    const int row0 = btr * 128, col0 = btc * 128;
    const int lane = tid & 63, wave = tid >> 6;
    const int wr = (wave >> 1) * 64, wc = (wave & 1) * 64;
    const int tx = lane & 15, quad = lane >> 4;

    f32x4 acc[4][4] = {};

    for (int k0 = 0; k0 < Kd; k0 += 64) {
#pragma unroll
        for (int l = 0; l < 4; ++l) {
            const int lin = l * 2048 + tid * 8;
            const int r = lin >> 6, c = lin & 63;
            gload_lds16(A + (size_t)(row0 + r) * Kd + k0 + c, &As[lin]);
        }
#pragma unroll
        for (int l = 0; l < 4; ++l) {
            const int lin = l * 2048 + tid * 8;
            const int r = lin >> 6, c = lin & 63;
            gload_lds16(Bm + (size_t)(col0 + r) * Kd + k0 + c, &Bs[lin]);
        }
        __syncthreads();
#pragma unroll
        for (int ks = 0; ks < 2; ++ks) {
            bf16x8 af[4], bfr[4];
#pragma unroll
            for (int i = 0; i < 4; ++i)
                af[i] = *(const bf16x8*)&As[(wr + i * 16 + tx) * 64 + ks * 32 + quad * 8];
#pragma unroll
            for (int j = 0; j < 4; ++j)
                bfr[j] = *(const bf16x8*)&Bs[(wc + j * 16 + tx) * 64 + ks * 32 + quad * 8];
#pragma unroll
            for (int i = 0; i < 4; ++i)
#pragma unroll
                for (int j = 0; j < 4; ++j)
                    acc[i][j] = __builtin_amdgcn_mfma_f32_16x16x32_bf16(
                        af[i], bfr[j], acc[i][j], 0, 0, 0);
        }
        __syncthreads();
    }

    if (EPI == EPI_LOSS) {
        float* loss = (float*)Cout;
        const float inv_n = 1.0f / (float)N;
#pragma unroll
        for (int i = 0; i < 4; ++i) {
#pragma unroll
            for (int r = 0; r < 4; ++r) {
                const int row = row0 + wr + i * 16 + quad * 4 + r;
                float s = 0.f;
#pragma unroll
                for (int j = 0; j < 4; ++j) {
                    const int col = col0 + wc + j * 16 + tx;
                    const float d = acc[i][j][r] - X[(size_t)row * N + col];
                    s = fmaf(d, d, s);
                }
                s += __shfl_xor(s, 1, 64);
                s += __shfl_xor(s, 2, 64);
                s += __shfl_xor(s, 4, 64);
                s += __shfl_xor(s, 8, 64);
                if (tx == 0) atomicAdd(&loss[row], s * inv_n);
            }
        }
    } else {
        u16* C = (u16*)Cout;
#pragma unroll
        for (int i = 0; i < 4; ++i)
#pragma unroll
            for (int j = 0; j < 4; ++j) {
                const int col = wc + j * 16 + tx;
                float b = (EPI == EPI_BIAS_BF16) ? bias[col0 + col] : 0.f;
#pragma unroll
                for (int r = 0; r < 4; ++r) {
                    const int row = wr + i * 16 + quad * 4 + r;
                    float v = acc[i][j][r];
                    if (EPI == EPI_BIAS_BF16) v = fmaf(v, alpha, -b);
                    smem[row * STG + col] = f2bf(v);
                }
            }
        __syncthreads();
        const int rr = tid >> 1, half = (tid & 1) * 64;
#pragma unroll
        for (int u = 0; u < 8; ++u) {
            *(uint4*)(C + (size_t)(row0 + rr) * N + col0 + half + u * 8) =
                *(const uint4*)&smem[rr * STG + half + u * 8];
        }
    }
}

// ---------------------------------------------------------------------------
// MFMA bf16 GEMM variant (64x128 tile) for the (B,E)-output GEMMs.
// ---------------------------------------------------------------------------
__global__ __launch_bounds__(256) void mfma_gemm64_kernel(
    const u16* __restrict__ A, const u16* __restrict__ Bm,
    u16* __restrict__ C, int M, int N, int Kd) {
    __shared__ u16 smem[12288];
    u16* As = smem;
    u16* Bs = smem + 4096;
    const int tid = threadIdx.x;
    int btr, btc;
    swizzle_tiles(btr, btc);
    const int row0 = btr * 64, col0 = btc * 128;
    const int lane = tid & 63, wave = tid >> 6;
    const int wr = (wave >> 1) * 32, wc = (wave & 1) * 64;
    const int tx = lane & 15, quad = lane >> 4;

    f32x4 acc[2][4] = {};

    for (int k0 = 0; k0 < Kd; k0 += 64) {
#pragma unroll
        for (int l = 0; l < 2; ++l) {
            const int lin = l * 2048 + tid * 8;
            const int r = lin >> 6, c = lin & 63;
            gload_lds16(A + (size_t)(row0 + r) * Kd + k0 + c, &As[lin]);
        }
#pragma unroll
        for (int l = 0; l < 4; ++l) {
            const int lin = l * 2048 + tid * 8;
            const int r = lin >> 6, c = lin & 63;
            gload_lds16(Bm + (size_t)(col0 + r) * Kd + k0 + c, &Bs[lin]);
        }
        __syncthreads();
#pragma unroll
        for (int ks = 0; ks < 2; ++ks) {
            bf16x8 af[2], bfr[4];
#pragma unroll
            for (int i = 0; i < 2; ++i)
                af[i] = *(const bf16x8*)&As[(wr + i * 16 + tx) * 64 + ks * 32 + quad * 8];
#pragma unroll
            for (int j = 0; j < 4; ++j)
                bfr[j] = *(const bf16x8*)&Bs[(wc + j * 16 + tx) * 64 + ks * 32 + quad * 8];
#pragma unroll
            for (int i = 0; i < 2; ++i)
#pragma unroll
                for (int j = 0; j < 4; ++j)
                    acc[i][j] = __builtin_amdgcn_mfma_f32_16x16x32_bf16(
                        af[i], bfr[j], acc[i][j], 0, 0, 0);
        }
        __syncthreads();
    }

#pragma unroll
    for (int i = 0; i < 2; ++i)
#pragma unroll
        for (int j = 0; j < 4; ++j)
#pragma unroll
            for (int r = 0; r < 4; ++r) {
                const int row = wr + i * 16 + quad * 4 + r;
                const int col = wc + j * 16 + tx;
                smem[row * STG + col] = f2bf(acc[i][j][r]);
            }
    __syncthreads();
    const int rr = tid >> 2, qo = (tid & 3) * 32;
#pragma unroll
    for (int u = 0; u < 4; ++u) {
        *(uint4*)(C + (size_t)(row0 + rr) * N + col0 + qo + u * 8) =
            *(const uint4*)&smem[rr * STG + qo + u * 8];
    }
}

// ---------------------------------------------------------------------------
// FUSED loop-step kernel: for a 16-row band of z (B,E):
//   t[b,k] = (2/E) * sum_e z[b,e]*xbT[k,e] - c2b[k]   held entirely in VGPRs
//   REWEIGHT: out = pik*exp(t-m) / sum(pik*exp(t-m))      (P_NULL, x2 cancel)
//   DECODE:   out = exp(t-x2) / (P_NULL + sum(exp(t-x2))), x2 = mean(z^2)
// grid: B/16 = 512 blocks, 256 threads (4 waves). Wave w owns k-cols
// [w*512, w*512+512): 32 C-frags of 16x16 = 128 acc VGPRs.
// ---------------------------------------------------------------------------
enum { MODE_REWEIGHT = 0, MODE_DECODE = 1 };

template <int MODE>
__global__ __launch_bounds__(256) void step_fused_kernel(
    const u16* __restrict__ Z,      // (B,E) bf16
    const u16* __restrict__ XbT,    // (K,E) bf16
    const float* __restrict__ c2b,  // (K) f32
    const u16* __restrict__ Pik,    // (B,K) bf16 (REWEIGHT only)
    u16* __restrict__ Out) {        // (B,K) bf16
    __shared__ u16 Zs[16 * 256];    // 8 KB z band
    __shared__ float c2s[K];        // 8 KB bias
    __shared__ float red_m[4][16];
    __shared__ float red_s[4][16];
    __shared__ float rowx2[16];
    const int tid = threadIdx.x;
    const int lane = tid & 63, wave = tid >> 6;
    const int tx = lane & 15, quad = lane >> 4;
    const int row0 = blockIdx.x * 16;
    const int kwave = wave * 512;

    // stage z band (16x256 bf16 = 8 KB) and c2b (8 KB)
    gload_lds16(Z + (size_t)row0 * E + tid * 8, &Zs[tid * 8]);
    gload_lds16(Z + (size_t)row0 * E + 2048 + tid * 8, &Zs[2048 + tid * 8]);
    gload_lds16(c2b + tid * 4, &c2s[tid * 4]);
    gload_lds16(c2b + 1024 + tid * 4, &c2s[1024 + tid * 4]);
    __syncthreads();

    // A-frags: row = tx, reduction offset = s*32 + quad*8 (8 frags cover E=256)
    bf16x8 af[8];
#pragma unroll
    for (int s = 0; s < 8; ++s)
        af[s] = *(const bf16x8*)&Zs[tx * 256 + s * 32 + quad * 8];

    if (MODE == MODE_DECODE) {
        // x2[row=tx] = mean_e z^2 ; lane holds 64 e-elems, quad-shuffle completes row
        float s2 = 0.f;
#pragma unroll
        for (int s = 0; s < 8; ++s)
#pragma unroll
            for (int j = 0; j < 8; ++j) {
                const float zv = bf2f((u16)af[s][j]);
                s2 = fmaf(zv, zv, s2);
            }
        s2 += __shfl_xor(s2, 16, 64);
        s2 += __shfl_xor(s2, 32, 64);
        if (wave == 0 && quad == 0) rowx2[tx] = s2 * (1.0f / (float)E);
    }

    // main MFMA sweep: 32 C-frags (16 rows x 16 k-cols each)
    f32x4 acc[32];
#pragma unroll
    for (int c = 0; c < 32; ++c) {
        f32x4 a = {0.f, 0.f, 0.f, 0.f};
        const u16* bp = XbT + (size_t)(kwave + c * 16 + tx) * E + quad * 8;
#pragma unroll
        for (int s = 0; s < 8; ++s) {
            const bf16x8 bfr = *(const bf16x8*)(bp + s * 32);
            a = __builtin_amdgcn_mfma_f32_16x16x32_bf16(af[s], bfr, a, 0, 0, 0);
        }
        acc[c] = a;
    }

    // pass 1: t = acc*(2/E) - c2b[k]; per-row max (row = quad*4+r, col k = kwave+c*16+tx)
    const float ascale = 2.0f / (float)E;
    float mrow[4] = {-1e30f, -1e30f, -1e30f, -1e30f};
#pragma unroll
    for (int c = 0; c < 32; ++c) {
        const float cb = c2s[kwave + c * 16 + tx];
#pragma unroll
        for (int r = 0; r < 4; ++r) {
            const float v = fmaf(acc[c][r], ascale, -cb);
            acc[c][r] = v;
            mrow[r] = fmaxf(mrow[r], v);
        }
    }
#pragma unroll
    for (int r = 0; r < 4; ++r) {
        mrow[r] = fmaxf(mrow[r], __shfl_xor(mrow[r], 1, 64));
        mrow[r] = fmaxf(mrow[r], __shfl_xor(mrow[r], 2, 64));
        mrow[r] = fmaxf(mrow[r], __shfl_xor(mrow[r], 4, 64));
        mrow[r] = fmaxf(mrow[r], __shfl_xor(mrow[r], 8, 64));
    }
    if (tx == 0) {
#pragma unroll
        for (int r = 0; r < 4; ++r) red_m[wave][quad * 4 + r] = mrow[r];
    }
    __syncthreads();
    float M[4];
#pragma unroll
    for (int r = 0; r < 4; ++r) {
        const int row = quad * 4 + r;
        M[r] = fmaxf(fmaxf(red_m[0][row], red_m[1][row]),
                     fmaxf(red_m[2][row], red_m[3][row]));
    }

    // pass 2: w = exp(t - M) [* pik]; per-row sum
    float srow[4] = {0.f, 0.f, 0.f, 0.f};
#pragma unroll
    for (int c = 0; c < 32; ++c) {
#pragma unroll
        for (int r = 0; r < 4; ++r) {
            float w = __expf(acc[c][r] - M[r]);
            if (MODE == MODE_REWEIGHT)
                w *= bf2f(Pik[(size_t)(row0 + quad * 4 + r) * K + kwave + c * 16 + tx]);
            acc[c][r] = w;
            srow[r] += w;
        }
    }
#pragma unroll
    for (int r = 0; r < 4; ++r) {
        srow[r] += __shfl_xor(srow[r], 1, 64);
        srow[r] += __shfl_xor(srow[r], 2, 64);
        srow[r] += __shfl_xor(srow[r], 4, 64);
        srow[r] += __shfl_xor(srow[r], 8, 64);
    }
    if (tx == 0) {
#pragma unroll
        for (int r = 0; r < 4; ++r) red_s[wave][quad * 4 + r] = srow[r];
    }
    __syncthreads();

    float F[4];
#pragma unroll
    for (int r = 0; r < 4; ++r) {
        const int row = quad * 4 + r;
        const float S = red_s[0][row] + red_s[1][row] + red_s[2][row] + red_s[3][row];
        if (MODE == MODE_REWEIGHT) {
            F[r] = 1.0f / S;
        } else {
            const float em = __expf(M[r] - rowx2[row]);
            F[r] = em / (P_NULL + em * S);
        }
    }

    // pass 3: store bf16
#pragma unroll
    for (int c = 0; c < 32; ++c) {
#pragma unroll
        for (int r = 0; r < 4; ++r) {
            Out[(size_t)(row0 + quad * 4 + r) * K + kwave + c * 16 + tx] =
                f2bf(acc[c][r] * F[r]);
        }
    }
}

// ---------------------------------------------------------------------------
// Row softmax over K=2048 (bf16 in/out). One block (256 thr) per row.
// ---------------------------------------------------------------------------
__global__ __launch_bounds__(256) void softmax_bf_kernel(
    const u16* __restrict__ T, u16* __restrict__ P) {
    __shared__ float sm[4];
    const size_t base = (size_t)blockIdx.x * K + (size_t)threadIdx.x * 8;
    float v[8];
    unpack8(*(const uint4*)(T + base), v);
    float m = v[0];
#pragma unroll
    for (int i = 1; i < 8; ++i) m = fmaxf(m, v[i]);
    m = block_max256(m, sm);
    float s = 0.f;
#pragma unroll
    for (int i = 0; i < 8; ++i) {
        v[i] = __expf(v[i] - m);
        s += v[i];
    }
    s = block_sum256(s, sm);
    const float inv = 1.f / s;
#pragma unroll
    for (int i = 0; i < 8; ++i) v[i] *= inv;
    *(uint4*)(P + base) = pack8(v);
}

// ---------------------------------------------------------------------------
extern "C" void kernel_launch(void* const* d_in, const int* in_sizes, int n_in,
                              void* d_out, int out_size, void* d_ws, size_t ws_size,
                              hipStream_t stream) {
    const float* images = (const float*)d_in[0];  // (B,G)
    const float* xa     = (const float*)d_in[1];  // (G,K)
    const float* xb     = (const float*)d_in[2];  // (E,K)
    float* out = (float*)d_out;                   // (B,)

    // workspace carve-up (u16 elements, 16B-aligned regions)
    u16* img_bf = (u16*)d_ws;                      // B*G
    u16* xa_bf  = img_bf + (size_t)B * G;          // G*K
    u16* xaT_bf = xa_bf + (size_t)G * K;           // K*G
    u16* xb_bf  = xaT_bf + (size_t)K * G;          // E*K
    u16* xbT_bf = xb_bf + (size_t)E * K;           // K*E
    u16* pik_bf = xbT_bf + (size_t)K * E;          // B*K
    u16* t_bf   = pik_bf + (size_t)B * K;          // B*K (encode only)
    u16* xp_bf  = t_bf + (size_t)B * K;            // B*K
    u16* z_bf   = xp_bf + (size_t)B * K;           // B*E
    float* c2a  = (float*)(z_bf + (size_t)B * E);  // K
    float* c2b  = c2a + K;                         // K

    (void)hipMemsetAsync(d_out, 0, (size_t)B * sizeof(float), stream);
    (void)hipMemsetAsync(c2a, 0, (size_t)2 * K * sizeof(float), stream);

    // bf16 conversions + transposes
    f2bf_kernel<<<(B * G) / 2048, 256, 0, stream>>>(images, img_bf, B * G);
    f2bf_kernel<<<(G * K) / 2048, 256, 0, stream>>>(xa, xa_bf, G * K);
    f2bf_kernel<<<(E * K) / 2048, 256, 0, stream>>>(xb, xb_bf, E * K);
    transpose_bf_kernel<<<dim3(K / 32, G / 32), 256, 0, stream>>>(xa, xaT_bf, G, K);
    transpose_bf_kernel<<<dim3(K / 32, E / 32), 256, 0, stream>>>(xb, xbT_bf, E, K);

    // c2a[k] = mean_g xa[g,k]^2 ; c2b[k] = mean_e xb[e,k]^2
    colsq_kernel<<<dim3(K / 256, G / 128), 256, 0, stream>>>(xa, G, K, 1.0f / G, c2a);
    colsq_kernel<<<dim3(K / 256, E / 128), 256, 0, stream>>>(xb, E, K, 1.0f / E, c2b);

    // encode: t = images@xa * (2/G) - c2a ; pik = softmax(t)
    mfma_gemm_kernel<EPI_BIAS_BF16><<<dim3(K / 128, B / 128), 256, 0, stream>>>(
        img_bf, xaT_bf, t_bf, c2a, nullptr, B, K, G, 2.0f / (float)G);
    softmax_bf_kernel<<<B, 256, 0, stream>>>(t_bf, pik_bf);

    // z = pik @ xb^T
    mfma_gemm64_kernel<<<dim3(E / 128, B / 64), 256, 0, stream>>>(
        pik_bf, xb_bf, z_bf, B, E, K);

    for (int s = 0; s < N_STEP; ++s) {
        // fused: t = z@xb*(2/E) - c2b ; xp = pik*exp(t-m)/sum
        step_fused_kernel<MODE_REWEIGHT><<<B / 16, 256, 0, stream>>>(
            z_bf, xbT_bf, c2b, pik_bf, xp_bf);
        // z = xp @ xb^T
        mfma_gemm64_kernel<<<dim3(E / 128, B / 64), 256, 0, stream>>>(
            xp_bf, xb_bf, z_bf, B, E, K);
    }

    // fused decode: xq = exp(t - x2)/(P_NULL + sum)  (x2 computed inline)
    step_fused_kernel<MODE_DECODE><<<B / 16, 256, 0, stream>>>(
        z_bf, xbT_bf, c2b, nullptr, xp_bf);

    // recon = xq @ xa^T ; loss[b] = mean_g (recon - images)^2
    mfma_gemm_kernel<EPI_LOSS><<<dim3(G / 128, B / 128), 256, 0, stream>>>(
        xp_bf, xa_bf, out, nullptr, images, B, G, K, 1.0f);
}